// Round 1
// 86.667 us; speedup vs baseline: 1.1339x; 1.1339x over previous
//
#include <hip/hip_runtime.h>
#include <hip/hip_bf16.h>

#define N_NODES  12288
#define N_FEAT   256
#define KDIM     128
#define N_GRAPHS 192
#define NMAX     112          // LDS fast-path max graph size (mean 64, std ~8)
#define KSTRIDE_U 68          // Q/K LDS row stride in u32 (272 B; 2-way=free, 16B-aligned)
#define XS_STRIDE_U 132       // X LDS row stride in u32 (528 B; 2-way=free, 16B-aligned)

// workspace layout (bytes) — Qb/Kb retained for the (rare) slow path only
#define WS_STARTS 0
#define WS_WBUF   1024                                  // fp32 w [12288] (slow path only)
#define WS_QB     (WS_WBUF + N_NODES * 4)               // bf16 Q [12288][128] as u32[64]
#define WS_KB     (WS_QB + N_NODES * 64 * 4)            // bf16 K [12288][128] as u32[64]
#define WS_WT     (WS_KB + N_NODES * 64 * 4)            // bf16 Wt [256][256] as u32[128]

typedef __bf16 bf16x8 __attribute__((ext_vector_type(8)));
typedef float  f32x4  __attribute__((ext_vector_type(4)));

__device__ __forceinline__ unsigned bf16_rne(float f) {
  unsigned u = __float_as_uint(f);
  return (u + 0x7FFFu + ((u >> 16) & 1u)) >> 16;
}
__device__ __forceinline__ unsigned pack_bf16(float lo, float hi) {
  return bf16_rne(lo) | (bf16_rne(hi) << 16);
}
__device__ __forceinline__ float bf_lo(unsigned u) { return __uint_as_float(u << 16); }
__device__ __forceinline__ float bf_hi(unsigned u) { return __uint_as_float(u & 0xFFFF0000u); }

// ---------------------------------------------------------------------------
// Kernel 1: W pre-transpose to bf16 (Wt[n][k], packed u32 pairs) + segment
// starts (block n <= 192: starts[n] = lower_bound(batch, n); batch sorted).
// ---------------------------------------------------------------------------
__global__ __launch_bounds__(64) void wt_prep_k(const float* __restrict__ Wq,
                                                const float* __restrict__ Wk,
                                                const int* __restrict__ batch,
                                                unsigned* __restrict__ Wt,
                                                int* __restrict__ starts) {
  const int n = blockIdx.x;
  const int t = threadIdx.x;
  const float* src = (n < KDIM) ? (Wq + n) : (Wk + (n - KDIM));
  float f0 = src[(4 * t + 0) * KDIM];
  float f1 = src[(4 * t + 1) * KDIM];
  float f2 = src[(4 * t + 2) * KDIM];
  float f3 = src[(4 * t + 3) * KDIM];
  Wt[n * 128 + 2 * t]     = pack_bf16(f0, f1);
  Wt[n * 128 + 2 * t + 1] = pack_bf16(f2, f3);

  if (t == 0 && n <= N_GRAPHS) {
    int lo = 0, hi = N_NODES;
    while (lo < hi) {
      int mid = (lo + hi) >> 1;
      if (batch[mid] < n) lo = mid + 1; else hi = mid;
    }
    starts[n] = lo;
  }
}

// ---------------------------------------------------------------------------
// Kernel 2 (fused): per-graph projection + attention pooling. One 512-thr
// block (8 waves) per graph.
//
// Phase S: stage X_seg (n x 256 fp32 -> bf16) into LDS, zero-padded to the
//   strip boundary. B-fragments of Wt (wave w owns output colgroups 2w,2w+1;
//   2 x 8 ksteps x bf16x8 = 64 VGPR) hoisted from global before the barrier.
// Phase P: per 16-row strip, 16 MFMA/wave -> Q (cols 0-127, scaled 1/16) and
//   K (cols 128-255) packed bf16 into LDS (stride-68, identical layout to the
//   old global Qb/Kb rows). No global round-trip.
// Phase A: attention — wave s computes 16-row strip s (7 colgroups x 4
//   ksteps MFMA vs K_lds) -> in-wave softmax (quad shfl) -> column weights
//   reduced shfl{16,32} -> w_lds.
// Phase B: w2 = sum over waves; u[f] = sum_j w2[j] X[i0+j][f] (fp32 from
//   global, L2-hot — this block just fetched those lines); out[g] = u @ Wv.
// Slow path (n > NMAX, never triggered for this input distribution):
//   chunked projection through the same LDS tile into global Qb/Kb, then the
//   two-pass online-softmax with wbuf atomics (single block per graph).
// ---------------------------------------------------------------------------
__global__ __launch_bounds__(512) void attn_fused_k(const float* __restrict__ X,
                                                    const int* __restrict__ starts,
                                                    const unsigned* __restrict__ Wt,
                                                    const float* __restrict__ Wv,
                                                    float* __restrict__ out,
                                                    unsigned* __restrict__ Qb,
                                                    unsigned* __restrict__ Kb,
                                                    float* __restrict__ wbuf) {
  __shared__ unsigned Xs_u[NMAX * XS_STRIDE_U];   // 59136 B
  __shared__ unsigned Qs_u[NMAX * KSTRIDE_U];     // 30464 B
  __shared__ unsigned Ks_u[NMAX * KSTRIDE_U];     // 30464 B
  __shared__ float    w_lds[8][NMAX];             // 3584 B
  __shared__ float    red[2][256];                // 2048 B
  __shared__ float    Us[256];                    // 1024 B
  // total 126720 B -> 1 block/CU (grid = 192 < 256 CUs, so no occupancy loss)

  const int tid  = threadIdx.x;
  const int lane = tid & 63;
  const int wv   = tid >> 6;
  const int l15  = lane & 15;
  const int quad = lane >> 4;
  const int g    = blockIdx.x;

  const int i0 = starts[g];
  const int n  = starts[g + 1] - i0;
  const float BIG = 1e30f;
  const bool fast = (n <= NMAX);

  // ---- hoist B-frags: wave wv -> Wt rows [2wv*16, 2wv*16+16) and +16 ----
  bf16x8 bq0[8], bq1[8];
  {
    const unsigned* w0 = &Wt[(size_t)((2 * wv + 0) * 16 + l15) * 128 + quad * 4];
    const unsigned* w1 = &Wt[(size_t)((2 * wv + 1) * 16 + l15) * 128 + quad * 4];
#pragma unroll
    for (int ks = 0; ks < 8; ks++) {
      bq0[ks] = *(const bf16x8*)&w0[ks * 16];
      bq1[ks] = *(const bf16x8*)&w1[ks * 16];
    }
  }
  unsigned* dst_lds   = (wv < 4) ? Qs_u : Ks_u;
  const float scale   = (wv < 4) ? 0.0625f : 1.0f;
  const int cb0 = ((2 * wv + 0) & 7) * 16;
  const int cb1 = ((2 * wv + 1) & 7) * 16;

  if (fast) {
    const int ns   = (n + 15) >> 4;
    const int npad = ns * 16;

    // ---- Phase S: stage X tile (zero-padded to strip boundary) ----
    for (int idx = tid; idx < npad * 16; idx += 512) {
      int row = idx >> 4, seg = idx & 15;
      unsigned* dst = &Xs_u[row * XS_STRIDE_U + seg * 8];
      if (row < n) {
        const float* xp = &X[(size_t)(i0 + row) * N_FEAT + seg * 16];
        float4 a = *(const float4*)xp;
        float4 b = *(const float4*)(xp + 4);
        float4 c = *(const float4*)(xp + 8);
        float4 d = *(const float4*)(xp + 12);
        *(uint4*)dst       = make_uint4(pack_bf16(a.x, a.y), pack_bf16(a.z, a.w),
                                        pack_bf16(b.x, b.y), pack_bf16(b.z, b.w));
        *(uint4*)(dst + 4) = make_uint4(pack_bf16(c.x, c.y), pack_bf16(c.z, c.w),
                                        pack_bf16(d.x, d.y), pack_bf16(d.z, d.w));
      } else {
        *(uint4*)dst       = make_uint4(0u, 0u, 0u, 0u);
        *(uint4*)(dst + 4) = make_uint4(0u, 0u, 0u, 0u);
      }
    }
    __syncthreads();

    // ---- Phase P: projection into Qs/Ks LDS ----
    for (int s = 0; s < ns; s++) {
      f32x4 acc0 = (f32x4){0.f, 0.f, 0.f, 0.f};
      f32x4 acc1 = (f32x4){0.f, 0.f, 0.f, 0.f};
#pragma unroll
      for (int ks = 0; ks < 8; ks++) {
        bf16x8 a = *(const bf16x8*)&Xs_u[(s * 16 + l15) * XS_STRIDE_U + ks * 16 + quad * 4];
        acc0 = __builtin_amdgcn_mfma_f32_16x16x32_bf16(a, bq0[ks], acc0, 0, 0, 0);
        acc1 = __builtin_amdgcn_mfma_f32_16x16x32_bf16(a, bq1[ks], acc1, 0, 0, 0);
      }
      // C/D: col = l15 (within colgroup), row = s*16 + quad*4 + e
#pragma unroll
      for (int e = 0; e < 4; e++) {
        const int row = s * 16 + quad * 4 + e;
        unsigned b0 = bf16_rne(acc0[e] * scale);
        unsigned p0 = __shfl_xor((int)b0, 1);
        unsigned b1 = bf16_rne(acc1[e] * scale);
        unsigned p1 = __shfl_xor((int)b1, 1);
        if ((lane & 1) == 0) {
          dst_lds[row * KSTRIDE_U + ((cb0 + l15) >> 1)] = b0 | (p0 << 16);
          dst_lds[row * KSTRIDE_U + ((cb1 + l15) >> 1)] = b1 | (p1 << 16);
        }
      }
    }
    __syncthreads();

    // ---- Phase A: attention; wave s handles row strip s ----
    float wl[7];
#pragma unroll
    for (int f = 0; f < 7; f++) wl[f] = 0.f;

    if (wv < ns) {
      const int s = wv;
      const int arow = min(s * 16 + l15, n - 1);
      bf16x8 au[4];
#pragma unroll
      for (int ks = 0; ks < 4; ks++)
        au[ks] = *(const bf16x8*)&Qs_u[arow * KSTRIDE_U + ks * 16 + quad * 4];

      f32x4 acc[7];
#pragma unroll
      for (int f = 0; f < 7; f++) acc[f] = (f32x4){0.f, 0.f, 0.f, 0.f};
#pragma unroll
      for (int f = 0; f < 7; f++) {
#pragma unroll
        for (int ks = 0; ks < 4; ks++) {
          bf16x8 bu = *(const bf16x8*)&Ks_u[(f * 16 + l15) * KSTRIDE_U + ks * 16 + quad * 4];
          acc[f] = __builtin_amdgcn_mfma_f32_16x16x32_bf16(au[ks], bu, acc[f], 0, 0, 0);
        }
      }
#pragma unroll
      for (int f = 0; f < 7; f++)
        if (f * 16 + l15 >= n) {
          acc[f][0] = -BIG; acc[f][1] = -BIG; acc[f][2] = -BIG; acc[f][3] = -BIG;
        }

#pragma unroll
      for (int e = 0; e < 4; e++) {
        float m = -BIG;
#pragma unroll
        for (int f = 0; f < 7; f++) m = fmaxf(m, acc[f][e]);
        m = fmaxf(m, __shfl_xor(m, 1));
        m = fmaxf(m, __shfl_xor(m, 2));
        m = fmaxf(m, __shfl_xor(m, 4));
        m = fmaxf(m, __shfl_xor(m, 8));
        float p[7], l = 0.f;
#pragma unroll
        for (int f = 0; f < 7; f++) { p[f] = __expf(acc[f][e] - m); l += p[f]; }
        l += __shfl_xor(l, 1);
        l += __shfl_xor(l, 2);
        l += __shfl_xor(l, 4);
        l += __shfl_xor(l, 8);
        const int row = s * 16 + quad * 4 + e;
        float inv = (row < n) ? (1.f / l) : 0.f;
#pragma unroll
        for (int f = 0; f < 7; f++) wl[f] = fmaf(p[f], inv, wl[f]);
      }
    }

    // ---- reduce across quads (column j = f*16 + l15) ----
#pragma unroll
    for (int f = 0; f < 7; f++) {
      wl[f] += __shfl_xor(wl[f], 16);
      wl[f] += __shfl_xor(wl[f], 32);
    }
    if (lane < 16) {
#pragma unroll
      for (int f = 0; f < 7; f++) w_lds[wv][f * 16 + lane] = wl[f];
    }
    __syncthreads();

    // ---- w2[j] = sum over 8 waves ----
    if (tid < NMAX) {
      float t = 0.f;
#pragma unroll
      for (int k = 0; k < 8; k++) t += w_lds[k][tid];
      w_lds[0][tid] = t;
    }
    __syncthreads();
  } else {
    // ================= slow path (n > NMAX) =================
    for (int idx = tid; idx < n; idx += 512) wbuf[i0 + idx] = 0.f;

    // chunked projection through the LDS tile into global Qb/Kb
    for (int c0 = 0; c0 < n; c0 += NMAX) {
      const int cn  = min(NMAX, n - c0);
      const int cns = (cn + 15) >> 4;
      __syncthreads();   // protect Xs reuse across chunks
      for (int idx = tid; idx < cns * 16 * 16; idx += 512) {
        int row = idx >> 4, seg = idx & 15;
        unsigned* dst = &Xs_u[row * XS_STRIDE_U + seg * 8];
        if (row < cn) {
          const float* xp = &X[(size_t)(i0 + c0 + row) * N_FEAT + seg * 16];
          float4 a = *(const float4*)xp;
          float4 b = *(const float4*)(xp + 4);
          float4 c = *(const float4*)(xp + 8);
          float4 d = *(const float4*)(xp + 12);
          *(uint4*)dst       = make_uint4(pack_bf16(a.x, a.y), pack_bf16(a.z, a.w),
                                          pack_bf16(b.x, b.y), pack_bf16(b.z, b.w));
          *(uint4*)(dst + 4) = make_uint4(pack_bf16(c.x, c.y), pack_bf16(c.z, c.w),
                                          pack_bf16(d.x, d.y), pack_bf16(d.z, d.w));
        } else {
          *(uint4*)dst       = make_uint4(0u, 0u, 0u, 0u);
          *(uint4*)(dst + 4) = make_uint4(0u, 0u, 0u, 0u);
        }
      }
      __syncthreads();
      unsigned* dstg = (wv < 4) ? Qb : Kb;
      for (int s = 0; s < cns; s++) {
        f32x4 acc0 = (f32x4){0.f, 0.f, 0.f, 0.f};
        f32x4 acc1 = (f32x4){0.f, 0.f, 0.f, 0.f};
#pragma unroll
        for (int ks = 0; ks < 8; ks++) {
          bf16x8 a = *(const bf16x8*)&Xs_u[(s * 16 + l15) * XS_STRIDE_U + ks * 16 + quad * 4];
          acc0 = __builtin_amdgcn_mfma_f32_16x16x32_bf16(a, bq0[ks], acc0, 0, 0, 0);
          acc1 = __builtin_amdgcn_mfma_f32_16x16x32_bf16(a, bq1[ks], acc1, 0, 0, 0);
        }
#pragma unroll
        for (int e = 0; e < 4; e++) {
          const int row = s * 16 + quad * 4 + e;
          unsigned b0 = bf16_rne(acc0[e] * scale);
          unsigned p0 = __shfl_xor((int)b0, 1);
          unsigned b1 = bf16_rne(acc1[e] * scale);
          unsigned p1 = __shfl_xor((int)b1, 1);
          if ((lane & 1) == 0 && row < cn) {
            dstg[(size_t)(i0 + c0 + row) * 64 + ((cb0 + l15) >> 1)] = b0 | (p0 << 16);
            dstg[(size_t)(i0 + c0 + row) * 64 + ((cb1 + l15) >> 1)] = b1 | (p1 << 16);
          }
        }
      }
    }
    __threadfence();
    __syncthreads();

    // two-pass online softmax into wbuf (single block per graph -> race-free)
    for (int lr = wv; lr < n; lr += 8) {
      const uint4* qp4 = (const uint4*)&Qb[(size_t)(i0 + lr) * 64];
      float m_run = -BIG, l_run = 0.f;
      for (int jb = 0; jb < n; jb += 64) {
        int j = jb + lane;
        int jc = min(j, n - 1);
        const uint4* kp4 = (const uint4*)&Kb[(size_t)(i0 + jc) * 64];
        float s = 0.f;
        for (int c = 0; c < 16; c++) {
          uint4 Q1 = qp4[c];
          uint4 K1 = kp4[c];
          s = fmaf(bf_lo(Q1.x), bf_lo(K1.x), s); s = fmaf(bf_hi(Q1.x), bf_hi(K1.x), s);
          s = fmaf(bf_lo(Q1.y), bf_lo(K1.y), s); s = fmaf(bf_hi(Q1.y), bf_hi(K1.y), s);
          s = fmaf(bf_lo(Q1.z), bf_lo(K1.z), s); s = fmaf(bf_hi(Q1.z), bf_hi(K1.z), s);
          s = fmaf(bf_lo(Q1.w), bf_lo(K1.w), s); s = fmaf(bf_hi(Q1.w), bf_hi(K1.w), s);
        }
        if (j >= n) s = -BIG;
        float mc = s;
        for (int off = 32; off; off >>= 1) mc = fmaxf(mc, __shfl_xor(mc, off));
        float m_new = fmaxf(m_run, mc);
        float lc = __expf(s - m_new);
        for (int off = 32; off; off >>= 1) lc += __shfl_xor(lc, off);
        l_run = l_run * __expf(m_run - m_new) + lc;
        m_run = m_new;
      }
      float inv = 1.f / l_run;
      for (int jb = 0; jb < n; jb += 64) {
        int j = jb + lane;
        int jc = min(j, n - 1);
        const uint4* kp4 = (const uint4*)&Kb[(size_t)(i0 + jc) * 64];
        float s = 0.f;
        for (int c = 0; c < 16; c++) {
          uint4 Q1 = qp4[c];
          uint4 K1 = kp4[c];
          s = fmaf(bf_lo(Q1.x), bf_lo(K1.x), s); s = fmaf(bf_hi(Q1.x), bf_hi(K1.x), s);
          s = fmaf(bf_lo(Q1.y), bf_lo(K1.y), s); s = fmaf(bf_hi(Q1.y), bf_hi(K1.y), s);
          s = fmaf(bf_lo(Q1.z), bf_lo(K1.z), s); s = fmaf(bf_hi(Q1.z), bf_hi(K1.z), s);
          s = fmaf(bf_lo(Q1.w), bf_lo(K1.w), s); s = fmaf(bf_hi(Q1.w), bf_hi(K1.w), s);
        }
        if (j < n) atomicAdd(&wbuf[i0 + j], __expf(s - m_run) * inv);
      }
    }
    __threadfence();
    __syncthreads();
  }

  // ---- Phase B: u[f] = sum_j w[j] * X[i0+j][f] (fp32 global, L2-hot) ----
  const int f  = tid & 255;
  const int jp = tid >> 8;
  float u0 = 0.f, u1 = 0.f, u2 = 0.f, u3 = 0.f;
  if (fast) {
    int j = jp;
    for (; j + 6 < n; j += 8) {
      u0 = fmaf(w_lds[0][j],     X[(size_t)(i0 + j) * N_FEAT + f], u0);
      u1 = fmaf(w_lds[0][j + 2], X[(size_t)(i0 + j + 2) * N_FEAT + f], u1);
      u2 = fmaf(w_lds[0][j + 4], X[(size_t)(i0 + j + 4) * N_FEAT + f], u2);
      u3 = fmaf(w_lds[0][j + 6], X[(size_t)(i0 + j + 6) * N_FEAT + f], u3);
    }
    for (; j < n; j += 2)
      u0 = fmaf(w_lds[0][j], X[(size_t)(i0 + j) * N_FEAT + f], u0);
  } else {
    for (int j = jp; j < n; j += 2) {
      float wj = atomicAdd(&wbuf[i0 + j], 0.f);   // coherent read past L1
      u0 = fmaf(wj, X[(size_t)(i0 + j) * N_FEAT + f], u0);
    }
  }
  red[jp][f] = (u0 + u1) + (u2 + u3);
  __syncthreads();
  if (jp == 0) Us[f] = red[0][f] + red[1][f];
  __syncthreads();

  // ---- out[g][f] = sum_k u_k * Wv[k][f]  (2-way k-split) ----
  const int k0 = jp * 128;
  const float* wp = Wv + (size_t)k0 * N_FEAT + f;
  const float* us = &Us[k0];
  float a0 = 0.f, a1 = 0.f, a2 = 0.f, a3 = 0.f;
#pragma unroll 8
  for (int k = 0; k < 128; k += 4) {
    a0 = fmaf(us[k],     wp[(size_t)k * N_FEAT], a0);
    a1 = fmaf(us[k + 1], wp[(size_t)(k + 1) * N_FEAT], a1);
    a2 = fmaf(us[k + 2], wp[(size_t)(k + 2) * N_FEAT], a2);
    a3 = fmaf(us[k + 3], wp[(size_t)(k + 3) * N_FEAT], a3);
  }
  __syncthreads();
  red[jp][f] = (a0 + a1) + (a2 + a3);
  __syncthreads();
  if (jp == 0) out[g * N_FEAT + f] = red[0][f] + red[1][f];
}

// ---------------------------------------------------------------------------
extern "C" void kernel_launch(void* const* d_in, const int* in_sizes, int n_in,
                              void* d_out, int out_size, void* d_ws, size_t ws_size,
                              hipStream_t stream) {
  const float* X     = (const float*)d_in[0];
  const int*   batch = (const int*)d_in[1];
  const float* Wq    = (const float*)d_in[2];
  const float* Wk    = (const float*)d_in[3];
  const float* Wv    = (const float*)d_in[4];
  float* out = (float*)d_out;

  char* ws = (char*)d_ws;
  int*      starts = (int*)(ws + WS_STARTS);
  float*    wbuf   = (float*)(ws + WS_WBUF);
  unsigned* Qb     = (unsigned*)(ws + WS_QB);
  unsigned* Kb     = (unsigned*)(ws + WS_KB);
  unsigned* Wt     = (unsigned*)(ws + WS_WT);

  wt_prep_k<<<256, 64, 0, stream>>>(Wq, Wk, batch, Wt, starts);
  attn_fused_k<<<N_GRAPHS, 512, 0, stream>>>(X, starts, Wt, Wv, out, Qb, Kb, wbuf);
}

// Round 2
// 82.193 us; speedup vs baseline: 1.1956x; 1.0544x over previous
//
#include <hip/hip_runtime.h>
#include <hip/hip_bf16.h>

#define N_NODES  12288
#define N_FEAT   256
#define KDIM     128
#define N_GRAPHS 192
#define NMAX     112          // LDS fast-path max graph size (mean 64, std ~8)
#define KSTRIDE_U 68          // Q/K LDS row stride in u32 (272 B; 2-way=free, 16B-aligned)
#define XS_STRIDE_U 132       // X LDS row stride in u32 (528 B; 2-way=free, 16B-aligned)

// workspace layout (bytes) — wbuf/Qb/Kb used by the (rare) slow path only
#define WS_WBUF   1024                                  // fp32 w [12288]
#define WS_QB     (WS_WBUF + N_NODES * 4)               // bf16 Q [12288][128] as u32[64]
#define WS_KB     (WS_QB + N_NODES * 64 * 4)            // bf16 K [12288][128] as u32[64]

typedef __bf16 bf16x8 __attribute__((ext_vector_type(8)));
typedef float  f32x4  __attribute__((ext_vector_type(4)));

__device__ __forceinline__ unsigned bf16_rne(float f) {
  unsigned u = __float_as_uint(f);
  return (u + 0x7FFFu + ((u >> 16) & 1u)) >> 16;
}
__device__ __forceinline__ unsigned pack_bf16(float lo, float hi) {
  return bf16_rne(lo) | (bf16_rne(hi) << 16);
}
__device__ __forceinline__ float bf_lo(unsigned u) { return __uint_as_float(u << 16); }
__device__ __forceinline__ float bf_hi(unsigned u) { return __uint_as_float(u & 0xFFFF0000u); }

// 64-ary wave-parallel lower_bound on sorted batch: ~4 dependent L2 loads
// (vs 14 for scalar bisection). All lanes of the wave must call together.
__device__ __forceinline__ int lb64(const int* __restrict__ batch, int target, int lane) {
  int lo = 0, hi = N_NODES;          // lower bound lies in [lo, hi]
  while (hi > lo) {
    int w = hi - lo;
    int step = (w + 63) >> 6;
    int idx = lo + lane * step;
    bool lt = (idx < hi) && (batch[idx] < target);
    unsigned long long b = __ballot(lt);
    int c = __popcll(b);
    if (c == 0) {
      hi = lo;                       // batch[lo] >= target
    } else {
      int nhi = lo + c * step;       // probe c is >= target (or out of range)
      lo = lo + (c - 1) * step + 1;  // probe c-1 is < target
      hi = (nhi < hi) ? nhi : hi;
    }
  }
  return lo;
}

// ---------------------------------------------------------------------------
// Single fused kernel: per-graph projection + attention pooling. One 512-thr
// block (8 waves) per graph. No prep kernel, no inter-kernel drain.
//
// Phase W: wave wv gathers its two B-fragment column-groups straight from
//   fp32 Wq/Wk (bf16_rne at gather time — bit-identical to the old Wt path);
//   128 independent scalar loads issued first, hidden under Phase G+S.
// Phase G: segment bounds via 64-ary wave-parallel lower_bound (~4 dependent
//   L2 loads per bound), computed redundantly by every wave.
// Phase S: stage X_seg (n x 256 fp32 -> bf16) into LDS, zero-padded to the
//   strip boundary.
// Phase P: per 16-row strip, 16 MFMA/wave -> Q (cols 0-127, scaled 1/16) and
//   K (cols 128-255) packed bf16 into LDS (stride-68).
// Phase A: attention — wave s computes 16-row strip s (7 colgroups x 4
//   ksteps MFMA vs K_lds) -> in-wave softmax (quad shfl) -> column weights
//   reduced shfl{16,32} -> w_lds.
// Phase B: w2 = sum over waves; u[f] = sum_j w2[j] X[i0+j][f] (fp32 global,
//   L2-hot from Phase S); out[g] = u @ Wv.
// Slow path (n > NMAX, never triggered for this distribution): chunked
//   projection through the LDS tile into global Qb/Kb, then two-pass online
//   softmax into wbuf via atomics (single block per graph -> race-free).
// ---------------------------------------------------------------------------
__global__ __launch_bounds__(512) void attn_fused_k(const float* __restrict__ X,
                                                    const int* __restrict__ batch,
                                                    const float* __restrict__ Wq,
                                                    const float* __restrict__ Wk,
                                                    const float* __restrict__ Wv,
                                                    float* __restrict__ out,
                                                    unsigned* __restrict__ Qb,
                                                    unsigned* __restrict__ Kb,
                                                    float* __restrict__ wbuf) {
  __shared__ unsigned Xs_u[NMAX * XS_STRIDE_U];   // 59136 B
  __shared__ unsigned Qs_u[NMAX * KSTRIDE_U];     // 30464 B
  __shared__ unsigned Ks_u[NMAX * KSTRIDE_U];     // 30464 B
  __shared__ float    w_lds[8][NMAX];             // 3584 B
  __shared__ float    red[2][256];                // 2048 B
  __shared__ float    Us[256];                    // 1024 B
  // total 126720 B -> 1 block/CU (grid = 192 < 256 CUs, so no occupancy loss)

  const int tid  = threadIdx.x;
  const int lane = tid & 63;
  const int wv   = tid >> 6;
  const int l15  = lane & 15;
  const int quad = lane >> 4;
  const int g    = blockIdx.x;
  const float BIG = 1e30f;

  // ---- Phase W: gather B-frags from fp32 Wq/Wk (independent loads, issued
  // first so they stay in flight under Phase G's dependent search) ----
  union U8 { unsigned u[4]; bf16x8 v; };
  bf16x8 bq0[8], bq1[8];
  {
    const float* wsrc = (wv < 4) ? Wq : Wk;
    const int c0 = (wv & 3) * 32 + l15;
#pragma unroll
    for (int ks = 0; ks < 8; ks++) {
      U8 t0, t1;
#pragma unroll
      for (int p = 0; p < 4; p++) {
        const int k = ks * 32 + quad * 8 + 2 * p;
        const float* r0p = wsrc + (size_t)k * KDIM;
        const float* r1p = wsrc + (size_t)(k + 1) * KDIM;
        t0.u[p] = pack_bf16(r0p[c0], r1p[c0]);
        t1.u[p] = pack_bf16(r0p[c0 + 16], r1p[c0 + 16]);
      }
      bq0[ks] = t0.v;
      bq1[ks] = t1.v;
    }
  }

  // ---- Phase G: segment bounds (redundant per wave; ~8 dependent loads) ----
  const int i0 = lb64(batch, g, lane);
  const int n  = lb64(batch, g + 1, lane) - i0;
  const bool fast = (n <= NMAX);

  unsigned* dst_lds = (wv < 4) ? Qs_u : Ks_u;
  const float scale = (wv < 4) ? 0.0625f : 1.0f;
  const int cb0 = ((2 * wv + 0) & 7) * 16;
  const int cb1 = ((2 * wv + 1) & 7) * 16;

  if (fast) {
    const int ns   = (n + 15) >> 4;
    const int npad = ns * 16;

    // ---- Phase S: stage X tile (zero-padded to strip boundary) ----
    for (int idx = tid; idx < npad * 16; idx += 512) {
      int row = idx >> 4, seg = idx & 15;
      unsigned* dst = &Xs_u[row * XS_STRIDE_U + seg * 8];
      if (row < n) {
        const float* xp = &X[(size_t)(i0 + row) * N_FEAT + seg * 16];
        float4 a = *(const float4*)xp;
        float4 b = *(const float4*)(xp + 4);
        float4 c = *(const float4*)(xp + 8);
        float4 d = *(const float4*)(xp + 12);
        *(uint4*)dst       = make_uint4(pack_bf16(a.x, a.y), pack_bf16(a.z, a.w),
                                        pack_bf16(b.x, b.y), pack_bf16(b.z, b.w));
        *(uint4*)(dst + 4) = make_uint4(pack_bf16(c.x, c.y), pack_bf16(c.z, c.w),
                                        pack_bf16(d.x, d.y), pack_bf16(d.z, d.w));
      } else {
        *(uint4*)dst       = make_uint4(0u, 0u, 0u, 0u);
        *(uint4*)(dst + 4) = make_uint4(0u, 0u, 0u, 0u);
      }
    }
    __syncthreads();

    // ---- Phase P: projection into Qs/Ks LDS ----
    for (int s = 0; s < ns; s++) {
      f32x4 acc0 = (f32x4){0.f, 0.f, 0.f, 0.f};
      f32x4 acc1 = (f32x4){0.f, 0.f, 0.f, 0.f};
#pragma unroll
      for (int ks = 0; ks < 8; ks++) {
        bf16x8 a = *(const bf16x8*)&Xs_u[(s * 16 + l15) * XS_STRIDE_U + ks * 16 + quad * 4];
        acc0 = __builtin_amdgcn_mfma_f32_16x16x32_bf16(a, bq0[ks], acc0, 0, 0, 0);
        acc1 = __builtin_amdgcn_mfma_f32_16x16x32_bf16(a, bq1[ks], acc1, 0, 0, 0);
      }
      // C/D: col = l15 (within colgroup), row = s*16 + quad*4 + e
#pragma unroll
      for (int e = 0; e < 4; e++) {
        const int row = s * 16 + quad * 4 + e;
        unsigned b0 = bf16_rne(acc0[e] * scale);
        unsigned p0 = __shfl_xor((int)b0, 1);
        unsigned b1 = bf16_rne(acc1[e] * scale);
        unsigned p1 = __shfl_xor((int)b1, 1);
        if ((lane & 1) == 0) {
          dst_lds[row * KSTRIDE_U + ((cb0 + l15) >> 1)] = b0 | (p0 << 16);
          dst_lds[row * KSTRIDE_U + ((cb1 + l15) >> 1)] = b1 | (p1 << 16);
        }
      }
    }
    __syncthreads();

    // ---- Phase A: attention; wave s handles row strip s ----
    float wl[7];
#pragma unroll
    for (int f = 0; f < 7; f++) wl[f] = 0.f;

    if (wv < ns) {
      const int s = wv;
      const int arow = min(s * 16 + l15, n - 1);
      bf16x8 au[4];
#pragma unroll
      for (int ks = 0; ks < 4; ks++)
        au[ks] = *(const bf16x8*)&Qs_u[arow * KSTRIDE_U + ks * 16 + quad * 4];

      f32x4 acc[7];
#pragma unroll
      for (int f = 0; f < 7; f++) acc[f] = (f32x4){0.f, 0.f, 0.f, 0.f};
#pragma unroll
      for (int f = 0; f < 7; f++) {
#pragma unroll
        for (int ks = 0; ks < 4; ks++) {
          bf16x8 bu = *(const bf16x8*)&Ks_u[(f * 16 + l15) * KSTRIDE_U + ks * 16 + quad * 4];
          acc[f] = __builtin_amdgcn_mfma_f32_16x16x32_bf16(au[ks], bu, acc[f], 0, 0, 0);
        }
      }
#pragma unroll
      for (int f = 0; f < 7; f++)
        if (f * 16 + l15 >= n) {
          acc[f][0] = -BIG; acc[f][1] = -BIG; acc[f][2] = -BIG; acc[f][3] = -BIG;
        }

#pragma unroll
      for (int e = 0; e < 4; e++) {
        float m = -BIG;
#pragma unroll
        for (int f = 0; f < 7; f++) m = fmaxf(m, acc[f][e]);
        m = fmaxf(m, __shfl_xor(m, 1));
        m = fmaxf(m, __shfl_xor(m, 2));
        m = fmaxf(m, __shfl_xor(m, 4));
        m = fmaxf(m, __shfl_xor(m, 8));
        float p[7], l = 0.f;
#pragma unroll
        for (int f = 0; f < 7; f++) { p[f] = __expf(acc[f][e] - m); l += p[f]; }
        l += __shfl_xor(l, 1);
        l += __shfl_xor(l, 2);
        l += __shfl_xor(l, 4);
        l += __shfl_xor(l, 8);
        const int row = s * 16 + quad * 4 + e;
        float inv = (row < n) ? (1.f / l) : 0.f;
#pragma unroll
        for (int f = 0; f < 7; f++) wl[f] = fmaf(p[f], inv, wl[f]);
      }
    }

    // ---- reduce across quads (column j = f*16 + l15) ----
#pragma unroll
    for (int f = 0; f < 7; f++) {
      wl[f] += __shfl_xor(wl[f], 16);
      wl[f] += __shfl_xor(wl[f], 32);
    }
    if (lane < 16) {
#pragma unroll
      for (int f = 0; f < 7; f++) w_lds[wv][f * 16 + lane] = wl[f];
    }
    __syncthreads();

    // ---- w2[j] = sum over 8 waves ----
    if (tid < NMAX) {
      float t = 0.f;
#pragma unroll
      for (int k = 0; k < 8; k++) t += w_lds[k][tid];
      w_lds[0][tid] = t;
    }
    __syncthreads();
  } else {
    // ================= slow path (n > NMAX) =================
    for (int idx = tid; idx < n; idx += 512) wbuf[i0 + idx] = 0.f;

    // chunked projection through the LDS tile into global Qb/Kb
    for (int c0 = 0; c0 < n; c0 += NMAX) {
      const int cn  = min(NMAX, n - c0);
      const int cns = (cn + 15) >> 4;
      __syncthreads();   // protect Xs reuse across chunks
      for (int idx = tid; idx < cns * 16 * 16; idx += 512) {
        int row = idx >> 4, seg = idx & 15;
        unsigned* dst = &Xs_u[row * XS_STRIDE_U + seg * 8];
        if (row < cn) {
          const float* xp = &X[(size_t)(i0 + c0 + row) * N_FEAT + seg * 16];
          float4 a = *(const float4*)xp;
          float4 b = *(const float4*)(xp + 4);
          float4 c = *(const float4*)(xp + 8);
          float4 d = *(const float4*)(xp + 12);
          *(uint4*)dst       = make_uint4(pack_bf16(a.x, a.y), pack_bf16(a.z, a.w),
                                          pack_bf16(b.x, b.y), pack_bf16(b.z, b.w));
          *(uint4*)(dst + 4) = make_uint4(pack_bf16(c.x, c.y), pack_bf16(c.z, c.w),
                                          pack_bf16(d.x, d.y), pack_bf16(d.z, d.w));
        } else {
          *(uint4*)dst       = make_uint4(0u, 0u, 0u, 0u);
          *(uint4*)(dst + 4) = make_uint4(0u, 0u, 0u, 0u);
        }
      }
      __syncthreads();
      unsigned* dstg = (wv < 4) ? Qb : Kb;
      for (int s = 0; s < cns; s++) {
        f32x4 acc0 = (f32x4){0.f, 0.f, 0.f, 0.f};
        f32x4 acc1 = (f32x4){0.f, 0.f, 0.f, 0.f};
#pragma unroll
        for (int ks = 0; ks < 8; ks++) {
          bf16x8 a = *(const bf16x8*)&Xs_u[(s * 16 + l15) * XS_STRIDE_U + ks * 16 + quad * 4];
          acc0 = __builtin_amdgcn_mfma_f32_16x16x32_bf16(a, bq0[ks], acc0, 0, 0, 0);
          acc1 = __builtin_amdgcn_mfma_f32_16x16x32_bf16(a, bq1[ks], acc1, 0, 0, 0);
        }
#pragma unroll
        for (int e = 0; e < 4; e++) {
          const int row = s * 16 + quad * 4 + e;
          unsigned b0 = bf16_rne(acc0[e] * scale);
          unsigned p0 = __shfl_xor((int)b0, 1);
          unsigned b1 = bf16_rne(acc1[e] * scale);
          unsigned p1 = __shfl_xor((int)b1, 1);
          if ((lane & 1) == 0 && row < cn) {
            dstg[(size_t)(i0 + c0 + row) * 64 + ((cb0 + l15) >> 1)] = b0 | (p0 << 16);
            dstg[(size_t)(i0 + c0 + row) * 64 + ((cb1 + l15) >> 1)] = b1 | (p1 << 16);
          }
        }
      }
    }
    __threadfence();
    __syncthreads();

    // two-pass online softmax into wbuf (single block per graph -> race-free)
    for (int lr = wv; lr < n; lr += 8) {
      const uint4* qp4 = (const uint4*)&Qb[(size_t)(i0 + lr) * 64];
      float m_run = -BIG, l_run = 0.f;
      for (int jb = 0; jb < n; jb += 64) {
        int j = jb + lane;
        int jc = min(j, n - 1);
        const uint4* kp4 = (const uint4*)&Kb[(size_t)(i0 + jc) * 64];
        float s = 0.f;
        for (int c = 0; c < 16; c++) {
          uint4 Q1 = qp4[c];
          uint4 K1 = kp4[c];
          s = fmaf(bf_lo(Q1.x), bf_lo(K1.x), s); s = fmaf(bf_hi(Q1.x), bf_hi(K1.x), s);
          s = fmaf(bf_lo(Q1.y), bf_lo(K1.y), s); s = fmaf(bf_hi(Q1.y), bf_hi(K1.y), s);
          s = fmaf(bf_lo(Q1.z), bf_lo(K1.z), s); s = fmaf(bf_hi(Q1.z), bf_hi(K1.z), s);
          s = fmaf(bf_lo(Q1.w), bf_lo(K1.w), s); s = fmaf(bf_hi(Q1.w), bf_hi(K1.w), s);
        }
        if (j >= n) s = -BIG;
        float mc = s;
        for (int off = 32; off; off >>= 1) mc = fmaxf(mc, __shfl_xor(mc, off));
        float m_new = fmaxf(m_run, mc);
        float lc = __expf(s - m_new);
        for (int off = 32; off; off >>= 1) lc += __shfl_xor(lc, off);
        l_run = l_run * __expf(m_run - m_new) + lc;
        m_run = m_new;
      }
      float inv = 1.f / l_run;
      for (int jb = 0; jb < n; jb += 64) {
        int j = jb + lane;
        int jc = min(j, n - 1);
        const uint4* kp4 = (const uint4*)&Kb[(size_t)(i0 + jc) * 64];
        float s = 0.f;
        for (int c = 0; c < 16; c++) {
          uint4 Q1 = qp4[c];
          uint4 K1 = kp4[c];
          s = fmaf(bf_lo(Q1.x), bf_lo(K1.x), s); s = fmaf(bf_hi(Q1.x), bf_hi(K1.x), s);
          s = fmaf(bf_lo(Q1.y), bf_lo(K1.y), s); s = fmaf(bf_hi(Q1.y), bf_hi(K1.y), s);
          s = fmaf(bf_lo(Q1.z), bf_lo(K1.z), s); s = fmaf(bf_hi(Q1.z), bf_hi(K1.z), s);
          s = fmaf(bf_lo(Q1.w), bf_lo(K1.w), s); s = fmaf(bf_hi(Q1.w), bf_hi(K1.w), s);
        }
        if (j < n) atomicAdd(&wbuf[i0 + j], __expf(s - m_run) * inv);
      }
    }
    __threadfence();
    __syncthreads();
  }

  // ---- Phase B: u[f] = sum_j w[j] * X[i0+j][f] (fp32 global, L2-hot) ----
  const int f  = tid & 255;
  const int jp = tid >> 8;
  float u0 = 0.f, u1 = 0.f, u2 = 0.f, u3 = 0.f;
  if (fast) {
    int j = jp;
    for (; j + 6 < n; j += 8) {
      u0 = fmaf(w_lds[0][j],     X[(size_t)(i0 + j) * N_FEAT + f], u0);
      u1 = fmaf(w_lds[0][j + 2], X[(size_t)(i0 + j + 2) * N_FEAT + f], u1);
      u2 = fmaf(w_lds[0][j + 4], X[(size_t)(i0 + j + 4) * N_FEAT + f], u2);
      u3 = fmaf(w_lds[0][j + 6], X[(size_t)(i0 + j + 6) * N_FEAT + f], u3);
    }
    for (; j < n; j += 2)
      u0 = fmaf(w_lds[0][j], X[(size_t)(i0 + j) * N_FEAT + f], u0);
  } else {
    for (int j = jp; j < n; j += 2) {
      float wj = atomicAdd(&wbuf[i0 + j], 0.f);   // coherent read past L1
      u0 = fmaf(wj, X[(size_t)(i0 + j) * N_FEAT + f], u0);
    }
  }
  red[jp][f] = (u0 + u1) + (u2 + u3);
  __syncthreads();
  if (jp == 0) Us[f] = red[0][f] + red[1][f];
  __syncthreads();

  // ---- out[g][f] = sum_k u_k * Wv[k][f]  (2-way k-split) ----
  const int k0 = jp * 128;
  const float* wp = Wv + (size_t)k0 * N_FEAT + f;
  const float* us = &Us[k0];
  float a0 = 0.f, a1 = 0.f, a2 = 0.f, a3 = 0.f;
#pragma unroll 8
  for (int k = 0; k < 128; k += 4) {
    a0 = fmaf(us[k],     wp[(size_t)k * N_FEAT], a0);
    a1 = fmaf(us[k + 1], wp[(size_t)(k + 1) * N_FEAT], a1);
    a2 = fmaf(us[k + 2], wp[(size_t)(k + 2) * N_FEAT], a2);
    a3 = fmaf(us[k + 3], wp[(size_t)(k + 3) * N_FEAT], a3);
  }
  __syncthreads();
  red[jp][f] = (a0 + a1) + (a2 + a3);
  __syncthreads();
  if (jp == 0) out[g * N_FEAT + f] = red[0][f] + red[1][f];
}

// ---------------------------------------------------------------------------
extern "C" void kernel_launch(void* const* d_in, const int* in_sizes, int n_in,
                              void* d_out, int out_size, void* d_ws, size_t ws_size,
                              hipStream_t stream) {
  const float* X     = (const float*)d_in[0];
  const int*   batch = (const int*)d_in[1];
  const float* Wq    = (const float*)d_in[2];
  const float* Wk    = (const float*)d_in[3];
  const float* Wv    = (const float*)d_in[4];
  float* out = (float*)d_out;

  char* ws = (char*)d_ws;
  float*    wbuf = (float*)(ws + WS_WBUF);
  unsigned* Qb   = (unsigned*)(ws + WS_QB);
  unsigned* Kb   = (unsigned*)(ws + WS_KB);

  attn_fused_k<<<N_GRAPHS, 512, 0, stream>>>(X, batch, Wq, Wk, Wv, out, Qb, Kb, wbuf);
}

// Round 3
// 82.161 us; speedup vs baseline: 1.1960x; 1.0004x over previous
//
#include <hip/hip_runtime.h>
#include <hip/hip_bf16.h>

#define N_NODES  12288
#define N_FEAT   256
#define KDIM     128
#define N_GRAPHS 192
#define NMAX     112          // LDS fast-path max graph size (mean 64, std ~8)
#define KSTRIDE_U 68          // Q/K LDS row stride in u32 (272 B; 2-way=free, 16B-aligned)
#define XS_STRIDE_U 132       // X LDS row stride in u32 (528 B; 2-way=free, 16B-aligned)

// workspace layout (bytes) — wbuf/Qb/Kb used by the (rare) slow path only
#define WS_WBUF   1024                                  // fp32 w [12288]
#define WS_QB     (WS_WBUF + N_NODES * 4)               // bf16 Q [12288][128] as u32[64]
#define WS_KB     (WS_QB + N_NODES * 64 * 4)            // bf16 K [12288][128] as u32[64]

typedef __bf16 bf16x8 __attribute__((ext_vector_type(8)));
typedef float  f32x4  __attribute__((ext_vector_type(4)));

__device__ __forceinline__ unsigned bf16_rne(float f) {
  unsigned u = __float_as_uint(f);
  return (u + 0x7FFFu + ((u >> 16) & 1u)) >> 16;
}
__device__ __forceinline__ unsigned pack_bf16(float lo, float hi) {
  return bf16_rne(lo) | (bf16_rne(hi) << 16);
}
__device__ __forceinline__ float bf_lo(unsigned u) { return __uint_as_float(u << 16); }
__device__ __forceinline__ float bf_hi(unsigned u) { return __uint_as_float(u & 0xFFFF0000u); }

// 64-ary wave-parallel lower_bound on sorted batch (~3 dependent L2 loads).
// All lanes of the calling wave must participate.
__device__ __forceinline__ int lb64(const int* __restrict__ batch, int target, int lane) {
  int lo = 0, hi = N_NODES;
  while (hi > lo) {
    int w = hi - lo;
    int step = (w + 63) >> 6;
    int idx = lo + lane * step;
    bool lt = (idx < hi) && (batch[idx] < target);
    unsigned long long b = __ballot(lt);
    int c = __popcll(b);
    if (c == 0) {
      hi = lo;
    } else {
      int nhi = lo + c * step;
      lo = lo + (c - 1) * step + 1;
      hi = (nhi < hi) ? nhi : hi;
    }
  }
  return lo;
}

// ---------------------------------------------------------------------------
// Single fused kernel: per-graph projection + attention pooling.
// One 1024-thr block (16 waves, 4 waves/SIMD) per graph.
//
// Phase W: wave wv gathers ONE B-fragment colgroup (16 output cols) straight
//   from fp32 Wq/Wk (bf16_rne at gather time); 64 independent scalar loads
//   issued first so they fly under Phase G.
// Phase G: segment bounds via wave-parallel lower_bound, computed by waves
//   0/1 only, broadcast through LDS (one extra barrier).
// Phase S: stage X_seg (n x 256 fp32 -> bf16) into LDS, zero-padded.
// Phase P: per 16-row strip, 8-MFMA chain per wave -> its colgroup of
//   Q (scaled 1/16) or K packed bf16 into LDS (stride-68).
// Phase A: wave s computes row strip s (7 colgroups x 4 ksteps MFMA vs
//   K_lds) -> in-wave softmax (quad shfl) -> column weights -> w_lds.
// Phase B: w2 = sum over 16 waves; u[f] = sum_j w2[j] X[i0+j][f] (4-way
//   j-split, X L2-hot from Phase S); out[g] = u @ Wv (4-way k-split).
// Slow path (n > NMAX, not triggered for this distribution): chunked
//   projection into global Qb/Kb, two-pass online softmax into wbuf.
// ---------------------------------------------------------------------------
__global__ __launch_bounds__(1024) void attn_fused_k(const float* __restrict__ X,
                                                     const int* __restrict__ batch,
                                                     const float* __restrict__ Wq,
                                                     const float* __restrict__ Wk,
                                                     const float* __restrict__ Wv,
                                                     float* __restrict__ out,
                                                     unsigned* __restrict__ Qb,
                                                     unsigned* __restrict__ Kb,
                                                     float* __restrict__ wbuf) {
  __shared__ unsigned Xs_u[NMAX * XS_STRIDE_U];   // 59136 B
  __shared__ unsigned Qs_u[NMAX * KSTRIDE_U];     // 30464 B
  __shared__ unsigned Ks_u[NMAX * KSTRIDE_U];     // 30464 B
  __shared__ float    w_lds[16][NMAX];            // 7168 B
  __shared__ float    red[4][256];                // 4096 B
  __shared__ float    Us[256];                    // 1024 B
  __shared__ int      seg[2];
  // total ~132.4 KB -> 1 block/CU (grid = 192 <= 256 CUs, no occupancy loss)

  const int tid  = threadIdx.x;
  const int lane = tid & 63;
  const int wv   = tid >> 6;        // 0..15
  const int l15  = lane & 15;
  const int quad = lane >> 4;
  const int g    = blockIdx.x;
  const float BIG = 1e30f;

  // ---- Phase W: gather ONE colgroup of B-frags from fp32 Wq/Wk ----
  union U8 { unsigned u[4]; bf16x8 v; };
  bf16x8 bq[8];
  {
    const float* wsrc = (wv < 8) ? Wq : Wk;
    const int cw = (wv & 7) * 16 + l15;
#pragma unroll
    for (int ks = 0; ks < 8; ks++) {
      U8 t;
#pragma unroll
      for (int p = 0; p < 4; p++) {
        const int k = ks * 32 + quad * 8 + 2 * p;
        t.u[p] = pack_bf16(wsrc[(size_t)k * KDIM + cw],
                           wsrc[(size_t)(k + 1) * KDIM + cw]);
      }
      bq[ks] = t.v;
    }
  }

  // ---- Phase G: segment bounds (waves 0/1), broadcast via LDS ----
  if (wv == 0) {
    int r = lb64(batch, g, lane);
    if (lane == 0) seg[0] = r;
  } else if (wv == 1) {
    int r = lb64(batch, g + 1, lane);
    if (lane == 0) seg[1] = r;
  }
  __syncthreads();
  const int i0 = seg[0];
  const int n  = seg[1] - i0;
  const bool fast = (n <= NMAX);

  unsigned* dst_lds = (wv < 8) ? Qs_u : Ks_u;
  const float scale = (wv < 8) ? 0.0625f : 1.0f;
  const int cb = (wv & 7) * 16;

  if (fast) {
    const int ns   = (n + 15) >> 4;
    const int npad = ns * 16;

    // ---- Phase S: stage X tile (zero-padded to strip boundary) ----
    for (int idx = tid; idx < npad * 16; idx += 1024) {
      int row = idx >> 4, sg = idx & 15;
      unsigned* dst = &Xs_u[row * XS_STRIDE_U + sg * 8];
      if (row < n) {
        const float* xp = &X[(size_t)(i0 + row) * N_FEAT + sg * 16];
        float4 a = *(const float4*)xp;
        float4 b = *(const float4*)(xp + 4);
        float4 c = *(const float4*)(xp + 8);
        float4 d = *(const float4*)(xp + 12);
        *(uint4*)dst       = make_uint4(pack_bf16(a.x, a.y), pack_bf16(a.z, a.w),
                                        pack_bf16(b.x, b.y), pack_bf16(b.z, b.w));
        *(uint4*)(dst + 4) = make_uint4(pack_bf16(c.x, c.y), pack_bf16(c.z, c.w),
                                        pack_bf16(d.x, d.y), pack_bf16(d.z, d.w));
      } else {
        *(uint4*)dst       = make_uint4(0u, 0u, 0u, 0u);
        *(uint4*)(dst + 4) = make_uint4(0u, 0u, 0u, 0u);
      }
    }
    __syncthreads();

    // ---- Phase P: projection, one colgroup per wave ----
    for (int s = 0; s < ns; s++) {
      f32x4 acc = (f32x4){0.f, 0.f, 0.f, 0.f};
#pragma unroll
      for (int ks = 0; ks < 8; ks++) {
        bf16x8 a = *(const bf16x8*)&Xs_u[(s * 16 + l15) * XS_STRIDE_U + ks * 16 + quad * 4];
        acc = __builtin_amdgcn_mfma_f32_16x16x32_bf16(a, bq[ks], acc, 0, 0, 0);
      }
      // C/D: col = l15 (within colgroup), row = s*16 + quad*4 + e
#pragma unroll
      for (int e = 0; e < 4; e++) {
        const int row = s * 16 + quad * 4 + e;
        unsigned b0 = bf16_rne(acc[e] * scale);
        unsigned p0 = __shfl_xor((int)b0, 1);
        if ((lane & 1) == 0)
          dst_lds[row * KSTRIDE_U + ((cb + l15) >> 1)] = b0 | (p0 << 16);
      }
    }
    __syncthreads();

    // ---- Phase A: attention; wave s handles row strip s ----
    float wl[7];
#pragma unroll
    for (int f = 0; f < 7; f++) wl[f] = 0.f;

    if (wv < ns) {
      const int s = wv;
      const int arow = min(s * 16 + l15, n - 1);
      bf16x8 au[4];
#pragma unroll
      for (int ks = 0; ks < 4; ks++)
        au[ks] = *(const bf16x8*)&Qs_u[arow * KSTRIDE_U + ks * 16 + quad * 4];

      f32x4 acc[7];
#pragma unroll
      for (int f = 0; f < 7; f++) acc[f] = (f32x4){0.f, 0.f, 0.f, 0.f};
#pragma unroll
      for (int f = 0; f < 7; f++) {
#pragma unroll
        for (int ks = 0; ks < 4; ks++) {
          bf16x8 bu = *(const bf16x8*)&Ks_u[(f * 16 + l15) * KSTRIDE_U + ks * 16 + quad * 4];
          acc[f] = __builtin_amdgcn_mfma_f32_16x16x32_bf16(au[ks], bu, acc[f], 0, 0, 0);
        }
      }
#pragma unroll
      for (int f = 0; f < 7; f++)
        if (f * 16 + l15 >= n) {
          acc[f][0] = -BIG; acc[f][1] = -BIG; acc[f][2] = -BIG; acc[f][3] = -BIG;
        }

#pragma unroll
      for (int e = 0; e < 4; e++) {
        float m = -BIG;
#pragma unroll
        for (int f = 0; f < 7; f++) m = fmaxf(m, acc[f][e]);
        m = fmaxf(m, __shfl_xor(m, 1));
        m = fmaxf(m, __shfl_xor(m, 2));
        m = fmaxf(m, __shfl_xor(m, 4));
        m = fmaxf(m, __shfl_xor(m, 8));
        float p[7], l = 0.f;
#pragma unroll
        for (int f = 0; f < 7; f++) { p[f] = __expf(acc[f][e] - m); l += p[f]; }
        l += __shfl_xor(l, 1);
        l += __shfl_xor(l, 2);
        l += __shfl_xor(l, 4);
        l += __shfl_xor(l, 8);
        const int row = s * 16 + quad * 4 + e;
        float inv = (row < n) ? (1.f / l) : 0.f;
#pragma unroll
        for (int f = 0; f < 7; f++) wl[f] = fmaf(p[f], inv, wl[f]);
      }
    }

    // ---- reduce across quads (column j = f*16 + l15) ----
#pragma unroll
    for (int f = 0; f < 7; f++) {
      wl[f] += __shfl_xor(wl[f], 16);
      wl[f] += __shfl_xor(wl[f], 32);
    }
    if (lane < 16) {
#pragma unroll
      for (int f = 0; f < 7; f++) w_lds[wv][f * 16 + lane] = wl[f];
    }
    __syncthreads();

    // ---- w2[j] = sum over 16 waves ----
    if (tid < NMAX) {
      float t = 0.f;
#pragma unroll
      for (int k = 0; k < 16; k++) t += w_lds[k][tid];
      w_lds[0][tid] = t;
    }
    __syncthreads();
  } else {
    // ================= slow path (n > NMAX) =================
    for (int idx = tid; idx < n; idx += 1024) wbuf[i0 + idx] = 0.f;

    // chunked projection through the LDS tile into global Qb/Kb
    unsigned* dstg = (wv < 8) ? Qb : Kb;
    for (int ch = 0; ch < n; ch += NMAX) {
      const int cn  = min(NMAX, n - ch);
      const int cns = (cn + 15) >> 4;
      __syncthreads();   // protect Xs reuse across chunks
      for (int idx = tid; idx < cns * 16 * 16; idx += 1024) {
        int row = idx >> 4, sg = idx & 15;
        unsigned* dst = &Xs_u[row * XS_STRIDE_U + sg * 8];
        if (row < cn) {
          const float* xp = &X[(size_t)(i0 + ch + row) * N_FEAT + sg * 16];
          float4 a = *(const float4*)xp;
          float4 b = *(const float4*)(xp + 4);
          float4 c = *(const float4*)(xp + 8);
          float4 d = *(const float4*)(xp + 12);
          *(uint4*)dst       = make_uint4(pack_bf16(a.x, a.y), pack_bf16(a.z, a.w),
                                          pack_bf16(b.x, b.y), pack_bf16(b.z, b.w));
          *(uint4*)(dst + 4) = make_uint4(pack_bf16(c.x, c.y), pack_bf16(c.z, c.w),
                                          pack_bf16(d.x, d.y), pack_bf16(d.z, d.w));
        } else {
          *(uint4*)dst       = make_uint4(0u, 0u, 0u, 0u);
          *(uint4*)(dst + 4) = make_uint4(0u, 0u, 0u, 0u);
        }
      }
      __syncthreads();
      for (int s = 0; s < cns; s++) {
        f32x4 acc = (f32x4){0.f, 0.f, 0.f, 0.f};
#pragma unroll
        for (int ks = 0; ks < 8; ks++) {
          bf16x8 a = *(const bf16x8*)&Xs_u[(s * 16 + l15) * XS_STRIDE_U + ks * 16 + quad * 4];
          acc = __builtin_amdgcn_mfma_f32_16x16x32_bf16(a, bq[ks], acc, 0, 0, 0);
        }
#pragma unroll
        for (int e = 0; e < 4; e++) {
          const int row = s * 16 + quad * 4 + e;
          unsigned b0 = bf16_rne(acc[e] * scale);
          unsigned p0 = __shfl_xor((int)b0, 1);
          if ((lane & 1) == 0 && row < cn)
            dstg[(size_t)(i0 + ch + row) * 64 + ((cb + l15) >> 1)] = b0 | (p0 << 16);
        }
      }
    }
    __threadfence();
    __syncthreads();

    // two-pass online softmax into wbuf (single block per graph -> race-free)
    for (int lr = wv; lr < n; lr += 16) {
      const uint4* qp4 = (const uint4*)&Qb[(size_t)(i0 + lr) * 64];
      float m_run = -BIG, l_run = 0.f;
      for (int jb = 0; jb < n; jb += 64) {
        int j = jb + lane;
        int jc = min(j, n - 1);
        const uint4* kp4 = (const uint4*)&Kb[(size_t)(i0 + jc) * 64];
        float s = 0.f;
        for (int c = 0; c < 16; c++) {
          uint4 Q1 = qp4[c];
          uint4 K1 = kp4[c];
          s = fmaf(bf_lo(Q1.x), bf_lo(K1.x), s); s = fmaf(bf_hi(Q1.x), bf_hi(K1.x), s);
          s = fmaf(bf_lo(Q1.y), bf_lo(K1.y), s); s = fmaf(bf_hi(Q1.y), bf_hi(K1.y), s);
          s = fmaf(bf_lo(Q1.z), bf_lo(K1.z), s); s = fmaf(bf_hi(Q1.z), bf_hi(K1.z), s);
          s = fmaf(bf_lo(Q1.w), bf_lo(K1.w), s); s = fmaf(bf_hi(Q1.w), bf_hi(K1.w), s);
        }
        if (j >= n) s = -BIG;
        float mc = s;
        for (int off = 32; off; off >>= 1) mc = fmaxf(mc, __shfl_xor(mc, off));
        float m_new = fmaxf(m_run, mc);
        float lc = __expf(s - m_new);
        for (int off = 32; off; off >>= 1) lc += __shfl_xor(lc, off);
        l_run = l_run * __expf(m_run - m_new) + lc;
        m_run = m_new;
      }
      float inv = 1.f / l_run;
      for (int jb = 0; jb < n; jb += 64) {
        int j = jb + lane;
        int jc = min(j, n - 1);
        const uint4* kp4 = (const uint4*)&Kb[(size_t)(i0 + jc) * 64];
        float s = 0.f;
        for (int c = 0; c < 16; c++) {
          uint4 Q1 = qp4[c];
          uint4 K1 = kp4[c];
          s = fmaf(bf_lo(Q1.x), bf_lo(K1.x), s); s = fmaf(bf_hi(Q1.x), bf_hi(K1.x), s);
          s = fmaf(bf_lo(Q1.y), bf_lo(K1.y), s); s = fmaf(bf_hi(Q1.y), bf_hi(K1.y), s);
          s = fmaf(bf_lo(Q1.z), bf_lo(K1.z), s); s = fmaf(bf_hi(Q1.z), bf_hi(K1.z), s);
          s = fmaf(bf_lo(Q1.w), bf_lo(K1.w), s); s = fmaf(bf_hi(Q1.w), bf_hi(K1.w), s);
        }
        if (j < n) atomicAdd(&wbuf[i0 + j], __expf(s - m_run) * inv);
      }
    }
    __threadfence();
    __syncthreads();
  }

  // ---- Phase B: u[f] = sum_j w[j] * X[i0+j][f] (4-way j-split, L2-hot) ----
  const int f  = tid & 255;
  const int jp = tid >> 8;          // 0..3
  float u0 = 0.f, u1 = 0.f;
  if (fast) {
    int j = jp;
    for (; j + 4 < n; j += 8) {
      u0 = fmaf(w_lds[0][j],     X[(size_t)(i0 + j) * N_FEAT + f], u0);
      u1 = fmaf(w_lds[0][j + 4], X[(size_t)(i0 + j + 4) * N_FEAT + f], u1);
    }
    for (; j < n; j += 4)
      u0 = fmaf(w_lds[0][j], X[(size_t)(i0 + j) * N_FEAT + f], u0);
  } else {
    for (int j = jp; j < n; j += 4) {
      float wj = atomicAdd(&wbuf[i0 + j], 0.f);   // coherent read past L1
      u0 = fmaf(wj, X[(size_t)(i0 + j) * N_FEAT + f], u0);
    }
  }
  red[jp][f] = u0 + u1;
  __syncthreads();
  if (jp == 0) Us[f] = (red[0][f] + red[1][f]) + (red[2][f] + red[3][f]);
  __syncthreads();

  // ---- out[g][f] = sum_k u_k * Wv[k][f]  (4-way k-split) ----
  const int k0 = jp * 64;
  const float* wp = Wv + (size_t)k0 * N_FEAT + f;
  const float* us = &Us[k0];
  float a0 = 0.f, a1 = 0.f, a2 = 0.f, a3 = 0.f;
#pragma unroll 4
  for (int k = 0; k < 64; k += 4) {
    a0 = fmaf(us[k],     wp[(size_t)k * N_FEAT], a0);
    a1 = fmaf(us[k + 1], wp[(size_t)(k + 1) * N_FEAT], a1);
    a2 = fmaf(us[k + 2], wp[(size_t)(k + 2) * N_FEAT], a2);
    a3 = fmaf(us[k + 3], wp[(size_t)(k + 3) * N_FEAT], a3);
  }
  __syncthreads();
  red[jp][f] = (a0 + a1) + (a2 + a3);
  __syncthreads();
  if (jp == 0)
    out[g * N_FEAT + f] = (red[0][f] + red[1][f]) + (red[2][f] + red[3][f]);
}

// ---------------------------------------------------------------------------
extern "C" void kernel_launch(void* const* d_in, const int* in_sizes, int n_in,
                              void* d_out, int out_size, void* d_ws, size_t ws_size,
                              hipStream_t stream) {
  const float* X     = (const float*)d_in[0];
  const int*   batch = (const int*)d_in[1];
  const float* Wq    = (const float*)d_in[2];
  const float* Wk    = (const float*)d_in[3];
  const float* Wv    = (const float*)d_in[4];
  float* out = (float*)d_out;

  char* ws = (char*)d_ws;
  float*    wbuf = (float*)(ws + WS_WBUF);
  unsigned* Qb   = (unsigned*)(ws + WS_QB);
  unsigned* Kb   = (unsigned*)(ws + WS_KB);

  attn_fused_k<<<N_GRAPHS, 1024, 0, stream>>>(X, batch, Wq, Wk, Wv, out, Qb, Kb, wbuf);
}